// Round 1
// baseline (34794.830 us; speedup 1.0000x reference)
//
#include <hip/hip_runtime.h>
#include <hip/hip_bf16.h>
#include <math.h>

// ---- model constants (fixed by the problem) ----
#define NT_TOK 4096     // B*S tokens
#define BATCH 2
#define SEQ 2048
#define DIM 1024
#define NHQ 16
#define NKV 4
#define HDIM 64
#define FDIM 4096
#define NLAYER 8
#define WIN 1024
#define VOCAB 32000
#define EPS_F 1e-6f

#define MASKED_S (-1.0e38f)
#define M_INIT   (-1.0e37f)

// ---------------- embed: x = tok_emb[ids] * sqrt(D) ----------------
__global__ __launch_bounds__(256) void embed_k(const int* __restrict__ ids,
                                               const float* __restrict__ emb,
                                               float* __restrict__ x) {
    const int i = blockIdx.x * 256 + threadIdx.x;  // float4 index
    const int n = i >> 8;                          // 256 float4 per row
    const int c = i & 255;
    float4 e = ((const float4*)(emb + (size_t)ids[n] * DIM))[c];
    e.x *= 32.f; e.y *= 32.f; e.z *= 32.f; e.w *= 32.f;
    ((float4*)(x + (size_t)n * DIM))[c] = e;
}

// ---------------- rmsnorm over D=1024, one block per row ----------------
__device__ __forceinline__ float block_sum256(float v, float* red) {
    #pragma unroll
    for (int off = 32; off; off >>= 1) v += __shfl_xor(v, off, 64);
    const int wid = threadIdx.x >> 6;
    if ((threadIdx.x & 63) == 0) red[wid] = v;
    __syncthreads();
    return red[0] + red[1] + red[2] + red[3];
}

__global__ __launch_bounds__(256) void rmsnorm_k(const float* __restrict__ in,
                                                 const float* __restrict__ sc,
                                                 float* __restrict__ out) {
    __shared__ float red[4];
    const size_t row = blockIdx.x;
    float4 v = ((const float4*)(in + row * DIM))[threadIdx.x];
    float ss = v.x*v.x + v.y*v.y + v.z*v.z + v.w*v.w;
    float tot = block_sum256(ss, red);
    float r = rsqrtf(tot * (1.f / DIM) + EPS_F);
    float4 s4 = ((const float4*)sc)[threadIdx.x];
    float4 ov;
    ov.x = v.x * r * (1.f + s4.x);
    ov.y = v.y * r * (1.f + s4.y);
    ov.z = v.z * r * (1.f + s4.z);
    ov.w = v.w * r * (1.f + s4.w);
    ((float4*)(out + row * DIM))[threadIdx.x] = ov;
}

// x += rmsnorm(y, sc)
__global__ __launch_bounds__(256) void add_rmsnorm_k(float* __restrict__ x,
                                                     const float* __restrict__ y,
                                                     const float* __restrict__ sc) {
    __shared__ float red[4];
    const size_t row = blockIdx.x;
    float4 v = ((const float4*)(y + row * DIM))[threadIdx.x];
    float ss = v.x*v.x + v.y*v.y + v.z*v.z + v.w*v.w;
    float tot = block_sum256(ss, red);
    float r = rsqrtf(tot * (1.f / DIM) + EPS_F);
    float4 s4 = ((const float4*)sc)[threadIdx.x];
    float4 xv = ((const float4*)(x + row * DIM))[threadIdx.x];
    xv.x += v.x * r * (1.f + s4.x);
    xv.y += v.y * r * (1.f + s4.y);
    xv.z += v.z * r * (1.f + s4.z);
    xv.w += v.w * r * (1.f + s4.w);
    ((float4*)(x + row * DIM))[threadIdx.x] = xv;
}

// ---------------- per-head rmsnorm + RoPE (+ q scaling) ----------------
// buf laid out (NT, NHEADS, 64); one wave per (token, head)
template<int NHEADS, bool IS_Q>
__global__ __launch_bounds__(256) void qknorm_rope_k(float* __restrict__ buf,
                                                     const float* __restrict__ sc,
                                                     const float* __restrict__ cosT,
                                                     const float* __restrict__ sinT) {
    const int unit = blockIdx.x * 4 + (threadIdx.x >> 6);
    const int lane = threadIdx.x & 63;
    const int n = unit / NHEADS;
    const int pos = n & (SEQ - 1);
    float* p = buf + (size_t)unit * HDIM;
    float v = p[lane];
    float ss = v * v;
    #pragma unroll
    for (int off = 32; off; off >>= 1) ss += __shfl_xor(ss, off, 64);
    float r = rsqrtf(ss * (1.f / HDIM) + EPS_F);
    v = v * r * (1.f + sc[lane]);
    float partner = __shfl_xor(v, 32, 64);
    float cs = cosT[pos * HDIM + lane];
    float sn = sinT[pos * HDIM + lane];
    float rot = (lane < 32) ? -partner : partner;
    v = v * cs + rot * sn;
    if (IS_Q) v *= 0.125f;  // HD^-0.5
    p[lane] = v;
}

// ---------------- flash attention, lane-per-query ----------------
// q: (NT, 1024)  k,v: (NT, 256)  ctx: (NT, 1024)
template<bool WINDOWED>
__global__ __launch_bounds__(256) void attn_k(const float* __restrict__ qbuf,
                                              const float* __restrict__ kbuf,
                                              const float* __restrict__ vbuf,
                                              float* __restrict__ ctx) {
    __shared__ float Ks[64][64];
    __shared__ float Vs[64][64];
    const int t = threadIdx.x;
    const int qi = blockIdx.x * 256 + t;
    const int h = blockIdx.y;
    const int b = blockIdx.z;
    const int g = h >> 2;  // GROUP=4
    const size_t n = (size_t)b * SEQ + qi;

    float qreg[64];
    const float* qrow = qbuf + n * DIM + h * HDIM;
    #pragma unroll
    for (int d = 0; d < 64; d += 4) {
        float4 v4 = *(const float4*)(qrow + d);
        qreg[d] = v4.x; qreg[d+1] = v4.y; qreg[d+2] = v4.z; qreg[d+3] = v4.w;
    }
    float o[64];
    #pragma unroll
    for (int d = 0; d < 64; ++d) o[d] = 0.f;
    float mval = M_INIT, lsum = 0.f;

    int jstart = 0;
    if (WINDOWED) {
        int lo = blockIdx.x * 256 - WIN;
        if (lo > 0) jstart = lo & ~63;
    }
    const int jend = blockIdx.x * 256 + 256;
    const int lr = t >> 4, lc = (t & 15) * 4;

    for (int j0 = jstart; j0 < jend; j0 += 64) {
        __syncthreads();
        #pragma unroll
        for (int i = 0; i < 4; ++i) {
            const int row = lr + i * 16;
            const size_t src = ((size_t)b * SEQ + j0 + row) * (NKV * HDIM) + g * HDIM + lc;
            *(float4*)&Ks[row][lc] = *(const float4*)(kbuf + src);
            *(float4*)&Vs[row][lc] = *(const float4*)(vbuf + src);
        }
        __syncthreads();
        #pragma unroll 1
        for (int c = 0; c < 4; ++c) {   // 4 chunks of 16 keys
            float s[16];
            #pragma unroll
            for (int j = 0; j < 16; ++j) {
                const int jj = c * 16 + j;
                float s0 = 0.f, s1 = 0.f, s2 = 0.f, s3 = 0.f;
                #pragma unroll
                for (int d = 0; d < 64; d += 4) {
                    float4 kv = *(const float4*)&Ks[jj][d];  // broadcast read
                    s0 = fmaf(qreg[d],   kv.x, s0);
                    s1 = fmaf(qreg[d+1], kv.y, s1);
                    s2 = fmaf(qreg[d+2], kv.z, s2);
                    s3 = fmaf(qreg[d+3], kv.w, s3);
                }
                const int jg = j0 + jj;
                bool valid = (jg <= qi);
                if (WINDOWED) valid = valid && ((qi - jg) <= WIN);
                s[j] = valid ? ((s0 + s1) + (s2 + s3)) : MASKED_S;
            }
            float mt = s[0];
            #pragma unroll
            for (int j = 1; j < 16; ++j) mt = fmaxf(mt, s[j]);
            float mnew = fmaxf(mval, mt);
            float scale = __expf(mval - mnew);
            lsum *= scale;
            #pragma unroll
            for (int d = 0; d < 64; ++d) o[d] *= scale;
            mval = mnew;
            #pragma unroll
            for (int j = 0; j < 16; ++j) {
                float pv = __expf(s[j] - mval);  // masked -> underflow to 0
                lsum += pv;
                #pragma unroll
                for (int d = 0; d < 64; d += 4) {
                    float4 vv = *(const float4*)&Vs[c * 16 + j][d];  // broadcast
                    o[d]   = fmaf(pv, vv.x, o[d]);
                    o[d+1] = fmaf(pv, vv.y, o[d+1]);
                    o[d+2] = fmaf(pv, vv.z, o[d+2]);
                    o[d+3] = fmaf(pv, vv.w, o[d+3]);
                }
            }
        }
    }
    const float inv = 1.f / lsum;
    float* orow = ctx + n * DIM + h * HDIM;
    #pragma unroll
    for (int d = 0; d < 64; d += 4) {
        *(float4*)(orow + d) = make_float4(o[d]*inv, o[d+1]*inv, o[d+2]*inv, o[d+3]*inv);
    }
}

// ---------------- silu(a)*b -> a ----------------
__global__ __launch_bounds__(256) void silu_mul_k(float* __restrict__ a,
                                                  const float* __restrict__ b) {
    const size_t i = (size_t)blockIdx.x * 256 + threadIdx.x;
    float4 av = ((const float4*)a)[i];
    float4 bv = ((const float4*)b)[i];
    av.x = av.x / (1.f + __expf(-av.x)) * bv.x;
    av.y = av.y / (1.f + __expf(-av.y)) * bv.y;
    av.z = av.z / (1.f + __expf(-av.z)) * bv.z;
    av.w = av.w / (1.f + __expf(-av.w)) * bv.w;
    ((float4*)a)[i] = av;
}

// ---------------- fp32 tiled GEMM: C(MxN) = A(MxK) @ B ----------------
// BT=false: B is (K,N) row-major. BT=true: B is (N,K) row-major (C = A @ B^T).
// Requires M%128==0, N%128==0, K%16==0.
template<bool BT>
__global__ __launch_bounds__(256) void gemm_f32(const float* __restrict__ A,
                                                const float* __restrict__ B,
                                                float* __restrict__ C,
                                                int M, int N, int K) {
    __shared__ float As[16][128];
    __shared__ float Bs[16][128];
    const int tid = threadIdx.x;
    const int m0 = blockIdx.y * 128;
    const int n0 = blockIdx.x * 128;
    const int tx = tid & 15, ty = tid >> 4;
    const int ar = tid >> 1, ak = (tid & 1) * 8;   // A (and BT-B) load: row, k-offset
    const int bkr = tid >> 5, bc = (tid & 31) * 4; // NN-B load: k-row, col

    float acc[8][8];
    #pragma unroll
    for (int i = 0; i < 8; ++i)
        #pragma unroll
        for (int j = 0; j < 8; ++j) acc[i][j] = 0.f;

    for (int k0 = 0; k0 < K; k0 += 16) {
        __syncthreads();
        {
            const float* ap = A + (size_t)(m0 + ar) * K + k0 + ak;
            float4 a0 = *(const float4*)ap;
            float4 a1 = *(const float4*)(ap + 4);
            As[ak+0][ar] = a0.x; As[ak+1][ar] = a0.y;
            As[ak+2][ar] = a0.z; As[ak+3][ar] = a0.w;
            As[ak+4][ar] = a1.x; As[ak+5][ar] = a1.y;
            As[ak+6][ar] = a1.z; As[ak+7][ar] = a1.w;
        }
        if (BT) {
            const float* bp = B + (size_t)(n0 + ar) * K + k0 + ak;
            float4 b0 = *(const float4*)bp;
            float4 b1 = *(const float4*)(bp + 4);
            Bs[ak+0][ar] = b0.x; Bs[ak+1][ar] = b0.y;
            Bs[ak+2][ar] = b0.z; Bs[ak+3][ar] = b0.w;
            Bs[ak+4][ar] = b1.x; Bs[ak+5][ar] = b1.y;
            Bs[ak+6][ar] = b1.z; Bs[ak+7][ar] = b1.w;
        } else {
            *(float4*)&Bs[bkr][bc]     = *(const float4*)(B + (size_t)(k0 + bkr) * N + n0 + bc);
            *(float4*)&Bs[bkr + 8][bc] = *(const float4*)(B + (size_t)(k0 + bkr + 8) * N + n0 + bc);
        }
        __syncthreads();
        #pragma unroll
        for (int kk = 0; kk < 16; ++kk) {
            float a_[8], b_[8];
            *(float4*)&a_[0] = *(const float4*)&As[kk][ty * 8];
            *(float4*)&a_[4] = *(const float4*)&As[kk][ty * 8 + 4];
            *(float4*)&b_[0] = *(const float4*)&Bs[kk][tx * 8];
            *(float4*)&b_[4] = *(const float4*)&Bs[kk][tx * 8 + 4];
            #pragma unroll
            for (int i = 0; i < 8; ++i)
                #pragma unroll
                for (int j = 0; j < 8; ++j)
                    acc[i][j] = fmaf(a_[i], b_[j], acc[i][j]);
        }
    }
    #pragma unroll
    for (int i = 0; i < 8; ++i) {
        const size_t off = (size_t)(m0 + ty * 8 + i) * N + n0 + tx * 8;
        *(float4*)(C + off)     = make_float4(acc[i][0], acc[i][1], acc[i][2], acc[i][3]);
        *(float4*)(C + off + 4) = make_float4(acc[i][4], acc[i][5], acc[i][6], acc[i][7]);
    }
}

// ---------------- host orchestration ----------------
extern "C" void kernel_launch(void* const* d_in, const int* in_sizes, int n_in,
                              void* d_out, int out_size, void* d_ws, size_t ws_size,
                              hipStream_t stream) {
    const int*   ids  = (const int*)d_in[0];
    const float* emb  = (const float*)d_in[1];
    const float* Wq   = (const float*)d_in[2];
    const float* Wk   = (const float*)d_in[3];
    const float* Wv   = (const float*)d_in[4];
    const float* Wo   = (const float*)d_in[5];
    const float* W1   = (const float*)d_in[6];
    const float* W2   = (const float*)d_in[7];
    const float* W3   = (const float*)d_in[8];
    const float* n1   = (const float*)d_in[9];
    const float* n2   = (const float*)d_in[10];
    const float* n3   = (const float*)d_in[11];
    const float* n4   = (const float*)d_in[12];
    const float* qn   = (const float*)d_in[13];
    const float* kn   = (const float*)d_in[14];
    const float* nf   = (const float*)d_in[15];
    const float* cosT = (const float*)d_in[16];
    const float* sinT = (const float*)d_in[17];
    float* out = (float*)d_out;

    float* p  = (float*)d_ws;
    float* x  = p; p += (size_t)NT_TOK * DIM;
    float* h  = p; p += (size_t)NT_TOK * DIM;
    float* qb = p; p += (size_t)NT_TOK * DIM;
    float* kb = p; p += (size_t)NT_TOK * NKV * HDIM;
    float* vb = p; p += (size_t)NT_TOK * NKV * HDIM;
    float* tb = p; p += (size_t)NT_TOK * DIM;
    float* f1 = p; p += (size_t)NT_TOK * FDIM;
    float* f2 = p; p += (size_t)NT_TOK * FDIM;
    float* ctx = h;  // h is dead once Q/K/V projections are done

    embed_k<<<NT_TOK, 256, 0, stream>>>(ids, emb, x);

    for (int l = 0; l < NLAYER; ++l) {
        rmsnorm_k<<<NT_TOK, 256, 0, stream>>>(x, n1 + (size_t)l * DIM, h);

        gemm_f32<false><<<dim3(DIM / 128, NT_TOK / 128), 256, 0, stream>>>(
            h, Wq + (size_t)l * DIM * DIM, qb, NT_TOK, DIM, DIM);
        gemm_f32<false><<<dim3(256 / 128, NT_TOK / 128), 256, 0, stream>>>(
            h, Wk + (size_t)l * DIM * (NKV * HDIM), kb, NT_TOK, NKV * HDIM, DIM);
        gemm_f32<false><<<dim3(256 / 128, NT_TOK / 128), 256, 0, stream>>>(
            h, Wv + (size_t)l * DIM * (NKV * HDIM), vb, NT_TOK, NKV * HDIM, DIM);

        qknorm_rope_k<NHQ, true ><<<NT_TOK * NHQ / 4, 256, 0, stream>>>(qb, qn + (size_t)l * HDIM, cosT, sinT);
        qknorm_rope_k<NKV, false><<<NT_TOK * NKV / 4, 256, 0, stream>>>(kb, kn + (size_t)l * HDIM, cosT, sinT);

        if (l < NLAYER - 4)
            attn_k<true ><<<dim3(SEQ / 256, NHQ, BATCH), 256, 0, stream>>>(qb, kb, vb, ctx);
        else
            attn_k<false><<<dim3(SEQ / 256, NHQ, BATCH), 256, 0, stream>>>(qb, kb, vb, ctx);

        gemm_f32<false><<<dim3(DIM / 128, NT_TOK / 128), 256, 0, stream>>>(
            ctx, Wo + (size_t)l * DIM * DIM, tb, NT_TOK, DIM, DIM);
        add_rmsnorm_k<<<NT_TOK, 256, 0, stream>>>(x, tb, n2 + (size_t)l * DIM);

        rmsnorm_k<<<NT_TOK, 256, 0, stream>>>(x, n3 + (size_t)l * DIM, h);
        gemm_f32<false><<<dim3(FDIM / 128, NT_TOK / 128), 256, 0, stream>>>(
            h, W1 + (size_t)l * DIM * FDIM, f1, NT_TOK, FDIM, DIM);
        gemm_f32<false><<<dim3(FDIM / 128, NT_TOK / 128), 256, 0, stream>>>(
            h, W2 + (size_t)l * DIM * FDIM, f2, NT_TOK, FDIM, DIM);
        silu_mul_k<<<(NT_TOK * FDIM / 4) / 256, 256, 0, stream>>>(f1, f2);
        gemm_f32<false><<<dim3(DIM / 128, NT_TOK / 128), 256, 0, stream>>>(
            f1, W3 + (size_t)l * FDIM * DIM, tb, NT_TOK, DIM, FDIM);
        add_rmsnorm_k<<<NT_TOK, 256, 0, stream>>>(x, tb, n4 + (size_t)l * DIM);
    }

    rmsnorm_k<<<NT_TOK, 256, 0, stream>>>(x, nf, h);
    gemm_f32<true><<<dim3(VOCAB / 128, NT_TOK / 128), 256, 0, stream>>>(
        h, emb, out, NT_TOK, VOCAB, DIM);
}